// Round 2
// baseline (143.926 us; speedup 1.0000x reference)
//
#include <hip/hip_runtime.h>

#define LN_EPS 1e-5f

constexpr int Bn = 4, Nn = 256, Dn = 256, Hn = 256;

// ws layout (floats):
//   aA   @ 0        (1024*256)
//   bB   @ 262144   (1024*256)
//   bBt  @ 524288   (1024*256)  transposed per-batch: bBt[(b*H + h)*N + j]
//   rC   @ 786432   (1024 r + 4 C)   -- atomic accumulators, zeroed in gemm
//   rel  @ 787712   (1024)

// ---------------------------------------------------------------------------
// Kernel 1: aA[m,h] = x[m,:]@Wg[:D,h] + bg[h]   (half=0)
//           bB[m,h] = x[m,:]@Wg[D:,h]           (half=1), also writes bBt
// 4-row m-tiles, grid (256, 2), 256 threads. Block (0,0) zeroes rC.
// ---------------------------------------------------------------------------
__global__ __launch_bounds__(256) void gemm_ab_kernel(
    const float* __restrict__ x, const float* __restrict__ Wg,
    const float* __restrict__ bg, float* __restrict__ aA,
    float* __restrict__ bB, float* __restrict__ bBt, float* __restrict__ rC)
{
    int mt = blockIdx.x;     // 0..255
    int half = blockIdx.y;   // 0 -> a-part, 1 -> b-part
    int m0 = mt * 4;
    int t = threadIdx.x;

    if (mt == 0 && half == 0) {
        for (int k = t; k < 1028; k += 256) rC[k] = 0.0f;
    }

    __shared__ float xs[4][256];
    const float4* xsrc = reinterpret_cast<const float4*>(x + m0 * Dn);
    reinterpret_cast<float4*>(&xs[0][0])[t] = xsrc[t];
    __syncthreads();

    int h = t;
    const float* W = Wg + (half ? Dn * Hn : 0) + h;
    float binit = half ? 0.0f : bg[h];
    float acc[4] = {binit, binit, binit, binit};

    for (int d = 0; d < 256; d += 8) {
        float w0 = W[(d + 0) * Hn];
        float w1 = W[(d + 1) * Hn];
        float w2 = W[(d + 2) * Hn];
        float w3 = W[(d + 3) * Hn];
        float w4 = W[(d + 4) * Hn];
        float w5 = W[(d + 5) * Hn];
        float w6 = W[(d + 6) * Hn];
        float w7 = W[(d + 7) * Hn];
#pragma unroll
        for (int mm = 0; mm < 4; ++mm) {
            float4 xa = *reinterpret_cast<const float4*>(&xs[mm][d]);
            float4 xb = *reinterpret_cast<const float4*>(&xs[mm][d + 4]);
            float a = acc[mm];
            a = fmaf(xa.x, w0, a); a = fmaf(xa.y, w1, a);
            a = fmaf(xa.z, w2, a); a = fmaf(xa.w, w3, a);
            a = fmaf(xb.x, w4, a); a = fmaf(xb.y, w5, a);
            a = fmaf(xb.z, w6, a); a = fmaf(xb.w, w7, a);
            acc[mm] = a;
        }
    }

    if (half == 0) {
#pragma unroll
        for (int mm = 0; mm < 4; ++mm) aA[(m0 + mm) * Hn + h] = acc[mm];
    } else {
#pragma unroll
        for (int mm = 0; mm < 4; ++mm) bB[(m0 + mm) * Hn + h] = acc[mm];
        int b = m0 >> 8, i0 = m0 & 255;
        float4 v = make_float4(acc[0], acc[1], acc[2], acc[3]);
        *reinterpret_cast<float4*>(&bBt[(b * Hn + h) * Nn + i0]) = v;
    }
}

// ---------------------------------------------------------------------------
// Kernel 2: fused pair block. Block = (b, 4-row i-tile), 512 threads.
// Phase 1 (thread = j): LN stats per (i,j) row, reading bBt COALESCED along j.
//   Also reduces Sy = sum(-m*inv) -> atomicAdd into C[b].
// Phase 2 (thread = h): acc += inv_ij * relu(A_i[h]+b_j[h]) over j, coalesced
//   bB reads; 4 i-rows reduced in LDS, one atomicAdd into r[b,h] per block.
// ---------------------------------------------------------------------------
__global__ __launch_bounds__(512) void pair_kernel(
    const float* __restrict__ aA, const float* __restrict__ bB,
    const float* __restrict__ bBt, float* __restrict__ rC)
{
    int b  = blockIdx.x >> 6;
    int i0 = (blockIdx.x & 63) * 4;
    int t = threadIdx.x;
    __shared__ float A[4][256];
    __shared__ float invL[4][256];
    __shared__ float red[2][256];

    for (int k = t; k < 1024; k += 512)
        A[k >> 8][k & 255] = aA[(b * Nn + i0 + (k >> 8)) * Hn + (k & 255)];
    __syncthreads();

    int j = t & 255;
    int g = t >> 8;          // wave-uniform

    // ---- phase 1: row stats for i-rows {2g, 2g+1}, coalesced bBt ----
    {
        float s0 = 0.f, s1 = 0.f, q0 = 0.f, q1 = 0.f;
        const float* bt = bBt + b * Hn * Nn + j;
        const float* A0 = A[2 * g];
        const float* A1 = A[2 * g + 1];
#pragma unroll 2
        for (int h = 0; h < 256; h += 4) {
            float4 a0 = *reinterpret_cast<const float4*>(A0 + h);
            float4 a1 = *reinterpret_cast<const float4*>(A1 + h);
            float b0 = bt[(h + 0) << 8];
            float b1 = bt[(h + 1) << 8];
            float b2 = bt[(h + 2) << 8];
            float b3 = bt[(h + 3) << 8];
            float v;
            v = fmaxf(a0.x + b0, 0.f); s0 += v; q0 = fmaf(v, v, q0);
            v = fmaxf(a0.y + b1, 0.f); s0 += v; q0 = fmaf(v, v, q0);
            v = fmaxf(a0.z + b2, 0.f); s0 += v; q0 = fmaf(v, v, q0);
            v = fmaxf(a0.w + b3, 0.f); s0 += v; q0 = fmaf(v, v, q0);
            v = fmaxf(a1.x + b0, 0.f); s1 += v; q1 = fmaf(v, v, q1);
            v = fmaxf(a1.y + b1, 0.f); s1 += v; q1 = fmaf(v, v, q1);
            v = fmaxf(a1.z + b2, 0.f); s1 += v; q1 = fmaf(v, v, q1);
            v = fmaxf(a1.w + b3, 0.f); s1 += v; q1 = fmaf(v, v, q1);
        }
        float m0 = s0 * (1.f / 256.f);
        float m1 = s1 * (1.f / 256.f);
        float inv0 = rsqrtf(q0 * (1.f / 256.f) - m0 * m0 + LN_EPS);
        float inv1 = rsqrtf(q1 * (1.f / 256.f) - m1 * m1 + LN_EPS);
        invL[2 * g][j]     = inv0;
        invL[2 * g + 1][j] = inv1;
        float ysum = -(m0 * inv0) - (m1 * inv1);
#pragma unroll
        for (int off = 32; off >= 1; off >>= 1) ysum += __shfl_xor(ysum, off, 64);
        if ((t & 63) == 0) atomicAdd(&rC[1024 + b], ysum);
    }
    __syncthreads();

    // ---- phase 2: weighted accumulation, coalesced over h ----
    int h = t & 255;
    float a0 = A[2 * g][h];
    float a1 = A[2 * g + 1][h];
    float acc0 = 0.f, acc1 = 0.f;
    const float* bcol = bB + b * Nn * Hn + h;
#pragma unroll 4
    for (int j2 = 0; j2 < 256; ++j2) {
        float bb = bcol[j2 << 8];
        float i0v = invL[2 * g][j2];
        float i1v = invL[2 * g + 1][j2];
        acc0 = fmaf(i0v, fmaxf(a0 + bb, 0.f), acc0);
        acc1 = fmaf(i1v, fmaxf(a1 + bb, 0.f), acc1);
    }
    red[g][h] = acc0 + acc1;
    __syncthreads();
    if (g == 0) atomicAdd(&rC[b * Hn + h], red[0][h] + red[1][h]);
}

// ---------------------------------------------------------------------------
// Kernel 3: per-batch finish. 4 blocks x 1024 threads (h = t&255, q = t>>8).
//   rs[h] = g_gamma[h]*(r[b,h] + C[b]) + N^2*g_beta[h]
//   y[h]  = relu(rs @ Wf + bf) ; rel = LN(y)
// ---------------------------------------------------------------------------
__global__ __launch_bounds__(1024) void finish_kernel(
    const float* __restrict__ rC,
    const float* __restrict__ gg, const float* __restrict__ gb,
    const float* __restrict__ Wf, const float* __restrict__ bfv,
    const float* __restrict__ fg, const float* __restrict__ fb,
    float* __restrict__ rel)
{
    int b = blockIdx.x;
    int t = threadIdx.x;
    int h = t & 255;
    int q = t >> 8;

    __shared__ float rs[256];
    __shared__ float ysum[4][256];
    __shared__ float pS[16], pQ[16];

    if (q == 0)
        rs[h] = gg[h] * (rC[b * Hn + h] + rC[1024 + b]) + 65536.0f * gb[h];
    __syncthreads();

    float y = 0.f;
    const float* Wcol = Wf + (q * 64) * Hn + h;
#pragma unroll 8
    for (int k = 0; k < 64; ++k) y = fmaf(rs[q * 64 + k], Wcol[k * Hn], y);
    ysum[q][h] = y;
    __syncthreads();

    float v = fmaxf(ysum[0][h] + ysum[1][h] + ysum[2][h] + ysum[3][h] + bfv[h], 0.f);

    float sv = v, qv = v * v;
#pragma unroll
    for (int off = 32; off >= 1; off >>= 1) {
        sv += __shfl_xor(sv, off, 64);
        qv += __shfl_xor(qv, off, 64);
    }
    int wid = t >> 6, lane = t & 63;
    if (lane == 0) { pS[wid] = sv; pQ[wid] = qv; }
    __syncthreads();
    float S = 0.f, Q = 0.f;
#pragma unroll
    for (int w = 0; w < 16; ++w) { S += pS[w]; Q += pQ[w]; }
    float m = S * (1.f / 1024.f);
    float var = Q * (1.f / 1024.f) - m * m;
    float inv = rsqrtf(var + LN_EPS);

    if (q == 0)
        rel[b * Hn + h] = (v - m) * inv * fg[h] + fb[h];
}

// ---------------------------------------------------------------------------
// Kernel 4: out[b,n,d] = rel[b,d] + x[b,n,d], float4-vectorized.
// ---------------------------------------------------------------------------
__global__ __launch_bounds__(256) void add_kernel(
    const float* __restrict__ rel, const float* __restrict__ x,
    float* __restrict__ out)
{
    int idx = blockIdx.x * blockDim.x + threadIdx.x;   // float4 units
    int b = idx >> 14;
    int d4 = idx & 63;
    float4 r4 = reinterpret_cast<const float4*>(rel)[b * 64 + d4];
    float4 x4 = reinterpret_cast<const float4*>(x)[idx];
    float4 o;
    o.x = r4.x + x4.x;
    o.y = r4.y + x4.y;
    o.z = r4.z + x4.z;
    o.w = r4.w + x4.w;
    reinterpret_cast<float4*>(out)[idx] = o;
}

// ---------------------------------------------------------------------------
extern "C" void kernel_launch(void* const* d_in, const int* in_sizes, int n_in,
                              void* d_out, int out_size, void* d_ws, size_t ws_size,
                              hipStream_t stream)
{
    const float* x   = (const float*)d_in[0];
    const float* Wg  = (const float*)d_in[1];
    const float* bg  = (const float*)d_in[2];
    const float* gg  = (const float*)d_in[3];
    const float* gb  = (const float*)d_in[4];
    const float* Wf  = (const float*)d_in[5];
    const float* bfv = (const float*)d_in[6];
    const float* fg  = (const float*)d_in[7];
    const float* fb  = (const float*)d_in[8];
    float* out = (float*)d_out;

    float* ws   = (float*)d_ws;
    float* aA   = ws;                 // 1024*256
    float* bB   = ws + 262144;        // 1024*256
    float* bBt  = ws + 524288;        // 1024*256 transposed
    float* rC   = ws + 786432;        // 1024 + 4 atomic accumulators
    float* rel  = ws + 787712;        // 4*256

    gemm_ab_kernel<<<dim3(256, 2), 256, 0, stream>>>(x, Wg, bg, aA, bB, bBt, rC);
    pair_kernel<<<256, 512, 0, stream>>>(aA, bB, bBt, rC);
    finish_kernel<<<4, 1024, 0, stream>>>(rC, gg, gb, Wf, bfv, fg, fb, rel);
    add_kernel<<<256, 256, 0, stream>>>(rel, x, out);
}